// Round 20
// baseline (260.433 us; speedup 1.0000x reference)
//
#include <hip/hip_runtime.h>
#include <hip/hip_fp16.h>
#include <hip/hip_cooperative_groups.h>
#include <stdint.h>

namespace cg = cooperative_groups;

#define DIN 96
#define DP 48
#define NPOS (48*48*48)   // 110592
#define NG 1728           // 12^3
#define WIN3 343
#define NCH 64
#define NC2 32

// ===========================================================================
// FUSED cooperative kernel (grid-stride all phases; any grid size works).
// LDS: one 17.8KB arena; phase2 weights/f2s, phase3 sred (aliased).
// ===========================================================================
__global__ void fused_all(
    const float* __restrict__ feat,   // [64][96][96][96]
    const float* __restrict__ dw_w,   // [64][27]
    const float* __restrict__ dw_b,   // [64]
    const float* __restrict__ pw_w,   // [32][64]
    const float* __restrict__ pw_b,   // [32]
    const float* __restrict__ k_w,    // [64][32]
    const float* __restrict__ v_w,    // [64][32]
    const float* __restrict__ out_w,  // [3][64]
    const float* __restrict__ out_b,  // [3]
    __half* __restrict__ dwout,       // [64][NPOS] fp16 (ws)
    float* __restrict__ VP8,          // [NPOS][8]       (ws)
    float* __restrict__ out)          // [3][NG]
{
    cg::grid_group grid = cg::this_grid();
    const int tid = threadIdx.x;
    const int bid = blockIdx.x;
    const int nbk = gridDim.x;

    __shared__ __align__(16) char smem[17920];
    float*  swT = (float*)smem;                          // 8192 B
    float*  sb  = (float*)(smem + 8192);                 //  128 B
    float (*WC)[NC2]  = (float(*)[NC2])(smem + 8320);    // 1024 B
    __half (*f2s)[33] = (__half(*)[33])(smem + 9344);    // 8448 B
    float (*sred)[8]  = (float(*)[8])(smem + 9344);      // phase3 alias

    // ================= phase 1: depthwise conv (grid-stride 3456) ==========
    #pragma unroll 1
    for (int chunk = bid; chunk < 3456; chunk += nbk) {
        const int orig = (chunk & 7) * 432 + (chunk >> 3);   // XCD-chunked
        const int c  = orig / 54;
        const int bx = orig % 54;

        const int idx = bx * 256 + tid;               // 0..13823
        const int t   = idx % 12;
        const int oh  = (idx / 12) % 48;
        const int odp = idx / (12 * 48);

        const float* fc = feat + (size_t)c * (DIN * DIN * DIN);
        const float* wcp = dw_w + c * 27;
        float w[27];
        #pragma unroll
        for (int i = 0; i < 27; ++i) w[i] = wcp[i];
        const float b = dw_b[c];

        float acc[2][4];
        #pragma unroll
        for (int i = 0; i < 2; ++i)
            #pragma unroll
            for (int j = 0; j < 4; ++j) acc[i][j] = 0.0f;

        #pragma unroll
        for (int dd = 0; dd < 5; ++dd) {
            const int id = 4 * odp - 1 + dd;
            if (id >= 0) {
                #pragma unroll
                for (int kh = 0; kh < 3; ++kh) {
                    const int ih = 2 * oh - 1 + kh;
                    if (ih >= 0) {
                        const float* row = fc + ((size_t)id * DIN + ih) * DIN + 8 * t;
                        const float4 a4 = *(const float4*)(row);
                        const float4 b4 = *(const float4*)(row + 4);
                        const float  s  = (t > 0) ? row[-1] : 0.0f;
                        #pragma unroll
                        for (int half = 0; half < 2; ++half) {
                            if ((half == 0 && dd <= 2) || (half == 1 && dd >= 2)) {
                                const int kd = (half == 0) ? dd : dd - 2;
                                const float w0 = w[(kd * 3 + kh) * 3 + 0];
                                const float w1 = w[(kd * 3 + kh) * 3 + 1];
                                const float w2 = w[(kd * 3 + kh) * 3 + 2];
                                acc[half][0] = fmaf(s,    w0, fmaf(a4.x, w1, fmaf(a4.y, w2, acc[half][0])));
                                acc[half][1] = fmaf(a4.y, w0, fmaf(a4.z, w1, fmaf(a4.w, w2, acc[half][1])));
                                acc[half][2] = fmaf(a4.w, w0, fmaf(b4.x, w1, fmaf(b4.y, w2, acc[half][2])));
                                acc[half][3] = fmaf(b4.y, w0, fmaf(b4.z, w1, fmaf(b4.w, w2, acc[half][3])));
                            }
                        }
                    }
                }
            }
        }

        const size_t base = (size_t)c * NPOS + (((size_t)(2 * odp) * DP + oh) * DP) + 4 * t;
        {
            float2 pk;
            ((__half2*)&pk)[0] = __floats2half2_rn(acc[0][0] + b, acc[0][1] + b);
            ((__half2*)&pk)[1] = __floats2half2_rn(acc[0][2] + b, acc[0][3] + b);
            *(float2*)(dwout + base) = pk;
        }
        {
            float2 pk;
            ((__half2*)&pk)[0] = __floats2half2_rn(acc[1][0] + b, acc[1][1] + b);
            ((__half2*)&pk)[1] = __floats2half2_rn(acc[1][2] + b, acc[1][3] + b);
            *(float2*)(dwout + base + DP * DP) = pk;
        }
    }

    grid.sync();

    // ================= phase 2: pointwise + K/V proj (grid-stride 864) =====
    {
        for (int i = tid; i < NCH * NC2; i += 256) {
            const int o = i & 31, c = i >> 5;
            swT[i] = pw_w[o * NCH + c];
        }
        if (tid < NC2) sb[tid] = pw_b[tid];
        if (tid < 64) {                   // K rows, prescaled
            const int h = tid >> 5, o = tid & 31;
            WC[h][o] = k_w[(h * 32) * NC2 + o] * 0.17677669529663687f;
        } else {                          // W2 rows, r=0..5
            const int r = (tid - 64) >> 5, k = (tid - 64) & 31;
            const int h = r / 3, oo = r % 3;
            float a = 0.f;
            #pragma unroll
            for (int c = 0; c < NC2; ++c)
                a = fmaf(out_w[oo * NCH + h * 32 + c], v_w[(h * 32 + c) * NC2 + k], a);
            WC[2 + r][k] = a;
        }
        __syncthreads();

        const int oq = tid & 7;
        const int p4 = tid >> 3;

        #pragma unroll 1
        for (int chunk = bid; chunk < 864; chunk += nbk) {
            const size_t pos0 = (size_t)chunk * 128;

            float acc[4][4];
            #pragma unroll
            for (int i = 0; i < 4; ++i) {
                const float b = sb[oq * 4 + i];
                #pragma unroll
                for (int j = 0; j < 4; ++j) acc[i][j] = b;
            }

            const __half* xp = dwout + pos0 + 4 * (size_t)p4;
            #pragma unroll 4
            for (int c = 0; c < NCH; ++c) {
                const float2 raw = *(const float2*)(xp + (size_t)c * NPOS);
                const float2 x01 = __half22float2(((const __half2*)&raw)[0]);
                const float2 x23 = __half22float2(((const __half2*)&raw)[1]);
                const float4 w4 = *(const float4*)(swT + c * NC2 + oq * 4);
                const float xs[4] = {x01.x, x01.y, x23.x, x23.y};
                const float ws[4] = {w4.x, w4.y, w4.z, w4.w};
                #pragma unroll
                for (int i = 0; i < 4; ++i)
                    #pragma unroll
                    for (int j = 0; j < 4; ++j)
                        acc[i][j] = fmaf(ws[i], xs[j], acc[i][j]);
            }

            #pragma unroll
            for (int j = 0; j < 4; ++j) {
                const int pl = p4 * 4 + j;
                #pragma unroll
                for (int i = 0; i < 4; ++i)
                    f2s[pl][oq * 4 + i] = __float2half(fmaxf(acc[i][j], 0.f));
            }
            __syncthreads();

            const int q  = tid & 1;
            const int pl = tid >> 1;
            float a8[4] = {0.f, 0.f, 0.f, 0.f};
            #pragma unroll 8
            for (int o = 0; o < NC2; ++o) {
                const float x = __half2float(f2s[pl][o]);
                #pragma unroll
                for (int r = 0; r < 4; ++r)
                    a8[r] = fmaf(WC[q * 4 + r][o], x, a8[r]);
            }
            *(float4*)(VP8 + (pos0 + pl) * 8 + q * 4) = make_float4(a8[0], a8[1], a8[2], a8[3]);
            __syncthreads();   // f2s reused next chunk
        }
    }

    grid.sync();

    // ================= phase 3: windowed attention (grid-stride 1728) ======
    {
        const int lo_t[12] = {0,1,5,9,14,18,22,26,31,35,39,44};
        const int hi_t[12] = {4,8,12,16,21,25,29,33,38,42,46,48};
        const int lane = tid & 63;
        const int wv   = tid >> 6;
        const float NEG_INF = -__builtin_inff();

        #pragma unroll 1
        for (int g = bid; g < NG; g += nbk) {
            const int gz = g % 12, gy = (g / 12) % 12, gx = g / 144;
            const int lox = lo_t[gx], hix = hi_t[gx];
            const int loy = lo_t[gy], hiy = hi_t[gy];
            const int loz = lo_t[gz], hiz = hi_t[gz];

            float4 lo0, hi0, lo1, hi1;
            {
                const int s = tid;
                const int kd = s / 49, kh = (s / 7) % 7, kw = s % 7;
                const int ix = lox + kd, iy = loy + kh, iz = loz + kw;
                if (ix < hix && iy < hiy && iz < hiz) {
                    const int fv = (ix * DP + iy) * DP + iz;
                    const float4* p = (const float4*)(VP8 + (size_t)fv * 8);
                    lo0 = p[0]; hi0 = p[1];
                } else {
                    lo0 = make_float4(NEG_INF, NEG_INF, 0.f, 0.f);
                    hi0 = make_float4(0.f, 0.f, 0.f, 0.f);
                }
            }
            {
                const int s = tid + 256;
                lo1 = make_float4(NEG_INF, NEG_INF, 0.f, 0.f);
                hi1 = make_float4(0.f, 0.f, 0.f, 0.f);
                if (s < WIN3) {
                    const int kd = s / 49, kh = (s / 7) % 7, kw = s % 7;
                    const int ix = lox + kd, iy = loy + kh, iz = loz + kw;
                    if (ix < hix && iy < hiy && iz < hiz) {
                        const int fv = (ix * DP + iy) * DP + iz;
                        const float4* p = (const float4*)(VP8 + (size_t)fv * 8);
                        lo1 = p[0]; hi1 = p[1];
                    }
                }
            }

            float m0 = fmaxf(lo0.x, lo1.x);
            float m1 = fmaxf(lo0.y, lo1.y);
            #pragma unroll
            for (int off = 32; off; off >>= 1) {
                m0 = fmaxf(m0, __shfl_xor(m0, off));
                m1 = fmaxf(m1, __shfl_xor(m1, off));
            }
            if (lane == 0) { sred[wv][0] = m0; sred[wv][1] = m1; }
            __syncthreads();
            const float g0 = fmaxf(fmaxf(sred[0][0], sred[1][0]), fmaxf(sred[2][0], sred[3][0]));
            const float g1 = fmaxf(fmaxf(sred[0][1], sred[1][1]), fmaxf(sred[2][1], sred[3][1]));
            __syncthreads();

            const float e00 = expf(lo0.x - g0), e01 = expf(lo0.y - g1);
            const float e10 = expf(lo1.x - g0), e11 = expf(lo1.y - g1);

            float acc[8];
            acc[0] = e00 + e10;
            acc[1] = e01 + e11;
            acc[2] = e00 * lo0.z + e10 * lo1.z;
            acc[3] = e00 * lo0.w + e10 * lo1.w;
            acc[4] = e00 * hi0.x + e10 * hi1.x;
            acc[5] = e01 * hi0.y + e11 * hi1.y;
            acc[6] = e01 * hi0.z + e11 * hi1.z;
            acc[7] = e01 * hi0.w + e11 * hi1.w;

            #pragma unroll
            for (int j = 0; j < 8; ++j) {
                #pragma unroll
                for (int off = 32; off; off >>= 1) acc[j] += __shfl_xor(acc[j], off);
            }
            if (lane == 0) {
                #pragma unroll
                for (int j = 0; j < 8; ++j) sred[wv][j] = acc[j];
            }
            __syncthreads();

            if (tid < 3) {
                const float s0 = sred[0][0] + sred[1][0] + sred[2][0] + sred[3][0];
                const float s1 = sred[0][1] + sred[1][1] + sred[2][1] + sred[3][1];
                const float a0 = sred[0][2 + tid] + sred[1][2 + tid] + sred[2][2 + tid] + sred[3][2 + tid];
                const float a1 = sred[0][5 + tid] + sred[1][5 + tid] + sred[2][5 + tid] + sred[3][5 + tid];
                out[tid * NG + g] = out_b[tid] + a0 / s0 + a1 / s1;
            }
            __syncthreads();   // sred reused next g
        }
    }
}

// ===========================================================================
// FALLBACK: proven R16 three-kernel path (75.4us)
// ===========================================================================
__global__ __launch_bounds__(256) void dwconv8h(
    const float* __restrict__ feat, const float* __restrict__ dw_w,
    const float* __restrict__ dw_b, __half* __restrict__ dwout)
{
    const int bid  = blockIdx.x;
    const int orig = (bid & 7) * 432 + (bid >> 3);
    const int c    = orig / 54;
    const int bx   = orig % 54;

    const int idx = bx * 256 + threadIdx.x;
    const int t   = idx % 12;
    const int oh  = (idx / 12) % 48;
    const int odp = idx / (12 * 48);

    const float* fc = feat + (size_t)c * (DIN * DIN * DIN);
    const float* wc = dw_w + c * 27;
    float w[27];
    #pragma unroll
    for (int i = 0; i < 27; ++i) w[i] = wc[i];

    float acc[2][4];
    #pragma unroll
    for (int i = 0; i < 2; ++i)
        #pragma unroll
        for (int j = 0; j < 4; ++j) acc[i][j] = 0.0f;

    #pragma unroll
    for (int dd = 0; dd < 5; ++dd) {
        const int id = 4 * odp - 1 + dd;
        if (id >= 0) {
            #pragma unroll
            for (int kh = 0; kh < 3; ++kh) {
                const int ih = 2 * oh - 1 + kh;
                if (ih >= 0) {
                    const float* row = fc + ((size_t)id * DIN + ih) * DIN + 8 * t;
                    const float4 a4 = *(const float4*)(row);
                    const float4 b4 = *(const float4*)(row + 4);
                    const float  s  = (t > 0) ? row[-1] : 0.0f;
                    #pragma unroll
                    for (int half = 0; half < 2; ++half) {
                        if ((half == 0 && dd <= 2) || (half == 1 && dd >= 2)) {
                            const int kd = (half == 0) ? dd : dd - 2;
                            const float w0 = w[(kd * 3 + kh) * 3 + 0];
                            const float w1 = w[(kd * 3 + kh) * 3 + 1];
                            const float w2 = w[(kd * 3 + kh) * 3 + 2];
                            acc[half][0] = fmaf(s,    w0, fmaf(a4.x, w1, fmaf(a4.y, w2, acc[half][0])));
                            acc[half][1] = fmaf(a4.y, w0, fmaf(a4.z, w1, fmaf(a4.w, w2, acc[half][1])));
                            acc[half][2] = fmaf(a4.w, w0, fmaf(b4.x, w1, fmaf(b4.y, w2, acc[half][2])));
                            acc[half][3] = fmaf(b4.y, w0, fmaf(b4.z, w1, fmaf(b4.w, w2, acc[half][3])));
                        }
                    }
                }
            }
        }
    }

    const float b = dw_b[c];
    const size_t base = (size_t)c * NPOS + (((size_t)(2 * odp) * DP + oh) * DP) + 4 * t;
    {
        float2 pk;
        ((__half2*)&pk)[0] = __floats2half2_rn(acc[0][0] + b, acc[0][1] + b);
        ((__half2*)&pk)[1] = __floats2half2_rn(acc[0][2] + b, acc[0][3] + b);
        *(float2*)(dwout + base) = pk;
    }
    {
        float2 pk;
        ((__half2*)&pk)[0] = __floats2half2_rn(acc[1][0] + b, acc[1][1] + b);
        ((__half2*)&pk)[1] = __floats2half2_rn(acc[1][2] + b, acc[1][3] + b);
        *(float2*)(dwout + base + DP * DP) = pk;
    }
}

__global__ __launch_bounds__(256) void pwk(
    const __half* __restrict__ dwout, const float* __restrict__ pw_w,
    const float* __restrict__ pw_b, const float* __restrict__ k_w,
    const float* __restrict__ v_w, const float* __restrict__ out_w,
    float* __restrict__ VP8)
{
    __shared__ float swT[NCH * NC2];
    __shared__ float sb[NC2];
    __shared__ float WC[8][NC2];
    __shared__ float f2s[128][33];
    const int tid = threadIdx.x;

    for (int i = tid; i < NCH * NC2; i += 256) {
        const int o = i & 31, c = i >> 5;
        swT[i] = pw_w[o * NCH + c];
    }
    if (tid < NC2) sb[tid] = pw_b[tid];
    if (tid < 64) {
        const int h = tid >> 5, o = tid & 31;
        WC[h][o] = k_w[(h * 32) * NC2 + o] * 0.17677669529663687f;
    } else {
        const int r = (tid - 64) >> 5, k = (tid - 64) & 31;
        const int h = r / 3, oo = r % 3;
        float a = 0.f;
        #pragma unroll
        for (int c = 0; c < NC2; ++c)
            a = fmaf(out_w[oo * NCH + h * 32 + c], v_w[(h * 32 + c) * NC2 + k], a);
        WC[2 + r][k] = a;
    }
    __syncthreads();

    const int oq = tid & 7;
    const int p4 = tid >> 3;
    const size_t pos0 = (size_t)blockIdx.x * 128;

    float acc[4][4];
    #pragma unroll
    for (int i = 0; i < 4; ++i) {
        const float b = sb[oq * 4 + i];
        #pragma unroll
        for (int j = 0; j < 4; ++j) acc[i][j] = b;
    }

    const __half* xp = dwout + pos0 + 4 * (size_t)p4;
    #pragma unroll 4
    for (int c = 0; c < NCH; ++c) {
        const float2 raw = *(const float2*)(xp + (size_t)c * NPOS);
        const float2 x01 = __half22float2(((const __half2*)&raw)[0]);
        const float2 x23 = __half22float2(((const __half2*)&raw)[1]);
        const float4 w4 = *(const float4*)(swT + c * NC2 + oq * 4);
        const float xs[4] = {x01.x, x01.y, x23.x, x23.y};
        const float ws[4] = {w4.x, w4.y, w4.z, w4.w};
        #pragma unroll
        for (int i = 0; i < 4; ++i)
            #pragma unroll
            for (int j = 0; j < 4; ++j)
                acc[i][j] = fmaf(ws[i], xs[j], acc[i][j]);
    }

    #pragma unroll
    for (int j = 0; j < 4; ++j) {
        const int pl = p4 * 4 + j;
        #pragma unroll
        for (int i = 0; i < 4; ++i)
            f2s[pl][oq * 4 + i] = fmaxf(acc[i][j], 0.f);
    }
    __syncthreads();

    const int q  = tid & 1;
    const int pl = tid >> 1;
    float a8[4] = {0.f, 0.f, 0.f, 0.f};
    #pragma unroll 8
    for (int o = 0; o < NC2; ++o) {
        const float x = f2s[pl][o];
        #pragma unroll
        for (int r = 0; r < 4; ++r)
            a8[r] = fmaf(WC[q * 4 + r][o], x, a8[r]);
    }
    *(float4*)(VP8 + (pos0 + pl) * 8 + q * 4) = make_float4(a8[0], a8[1], a8[2], a8[3]);
}

__global__ __launch_bounds__(256) void attn_vp(
    const float* __restrict__ VP8, const float* __restrict__ out_b,
    float* __restrict__ out)
{
    const int lo_t[12] = {0,1,5,9,14,18,22,26,31,35,39,44};
    const int hi_t[12] = {4,8,12,16,21,25,29,33,38,42,46,48};

    const int g    = blockIdx.x;
    const int tid  = threadIdx.x;
    const int lane = tid & 63;
    const int wv   = tid >> 6;

    const int gz = g % 12, gy = (g / 12) % 12, gx = g / 144;
    const int lox = lo_t[gx], hix = hi_t[gx];
    const int loy = lo_t[gy], hiy = hi_t[gy];
    const int loz = lo_t[gz], hiz = hi_t[gz];

    const float NEG_INF = -__builtin_inff();

    float4 lo0, hi0, lo1, hi1;
    {
        const int s = tid;
        const int kd = s / 49, kh = (s / 7) % 7, kw = s % 7;
        const int ix = lox + kd, iy = loy + kh, iz = loz + kw;
        if (ix < hix && iy < hiy && iz < hiz) {
            const int fv = (ix * DP + iy) * DP + iz;
            const float4* p = (const float4*)(VP8 + (size_t)fv * 8);
            lo0 = p[0]; hi0 = p[1];
        } else {
            lo0 = make_float4(NEG_INF, NEG_INF, 0.f, 0.f);
            hi0 = make_float4(0.f, 0.f, 0.f, 0.f);
        }
    }
    {
        const int s = tid + 256;
        lo1 = make_float4(NEG_INF, NEG_INF, 0.f, 0.f);
        hi1 = make_float4(0.f, 0.f, 0.f, 0.f);
        if (s < WIN3) {
            const int kd = s / 49, kh = (s / 7) % 7, kw = s % 7;
            const int ix = lox + kd, iy = loy + kh, iz = loz + kw;
            if (ix < hix && iy < hiy && iz < hiz) {
                const int fv = (ix * DP + iy) * DP + iz;
                const float4* p = (const float4*)(VP8 + (size_t)fv * 8);
                lo1 = p[0]; hi1 = p[1];
            }
        }
    }

    __shared__ float sred[4][8];

    float m0 = fmaxf(lo0.x, lo1.x);
    float m1 = fmaxf(lo0.y, lo1.y);
    #pragma unroll
    for (int off = 32; off; off >>= 1) {
        m0 = fmaxf(m0, __shfl_xor(m0, off));
        m1 = fmaxf(m1, __shfl_xor(m1, off));
    }
    if (lane == 0) { sred[wv][0] = m0; sred[wv][1] = m1; }
    __syncthreads();
    const float g0 = fmaxf(fmaxf(sred[0][0], sred[1][0]), fmaxf(sred[2][0], sred[3][0]));
    const float g1 = fmaxf(fmaxf(sred[0][1], sred[1][1]), fmaxf(sred[2][1], sred[3][1]));
    __syncthreads();

    const float e00 = expf(lo0.x - g0), e01 = expf(lo0.y - g1);
    const float e10 = expf(lo1.x - g0), e11 = expf(lo1.y - g1);

    float acc[8];
    acc[0] = e00 + e10;
    acc[1] = e01 + e11;
    acc[2] = e00 * lo0.z + e10 * lo1.z;
    acc[3] = e00 * lo0.w + e10 * lo1.w;
    acc[4] = e00 * hi0.x + e10 * hi1.x;
    acc[5] = e01 * hi0.y + e11 * hi1.y;
    acc[6] = e01 * hi0.z + e11 * hi1.z;
    acc[7] = e01 * hi0.w + e11 * hi1.w;

    #pragma unroll
    for (int j = 0; j < 8; ++j) {
        #pragma unroll
        for (int off = 32; off; off >>= 1) acc[j] += __shfl_xor(acc[j], off);
    }
    if (lane == 0) {
        #pragma unroll
        for (int j = 0; j < 8; ++j) sred[wv][j] = acc[j];
    }
    __syncthreads();

    if (tid < 3) {
        const float s0 = sred[0][0] + sred[1][0] + sred[2][0] + sred[3][0];
        const float s1 = sred[0][1] + sred[1][1] + sred[2][1] + sred[3][1];
        const float a0 = sred[0][2 + tid] + sred[1][2 + tid] + sred[2][2 + tid] + sred[3][2 + tid];
        const float a1 = sred[0][5 + tid] + sred[1][5 + tid] + sred[2][5 + tid] + sred[3][5 + tid];
        out[tid * NG + g] = out_b[tid] + a0 / s0 + a1 / s1;
    }
}

// ---------------------------------------------------------------------------
extern "C" void kernel_launch(void* const* d_in, const int* in_sizes, int n_in,
                              void* d_out, int out_size, void* d_ws, size_t ws_size,
                              hipStream_t stream) {
    const float* feat  = (const float*)d_in[0];
    const float* dw_w  = (const float*)d_in[1];
    const float* dw_b  = (const float*)d_in[2];
    const float* pw_w  = (const float*)d_in[3];
    const float* pw_b  = (const float*)d_in[4];
    const float* k_w   = (const float*)d_in[5];
    const float* v_w   = (const float*)d_in[6];
    const float* out_w = (const float*)d_in[7];
    const float* out_b = (const float*)d_in[8];
    float* out = (float*)d_out;

    __half* dwout = (__half*)d_ws;                              // [64][NPOS] 14 MB
    float*  VP8   = (float*)(dwout + (size_t)NCH * NPOS);       // [NPOS][8] 3.5 MB

    // Try cooperative fused path, sized by the runtime's own occupancy calc.
    bool done = false;
    int nb = 0;
    if (hipOccupancyMaxActiveBlocksPerMultiprocessor(&nb, fused_all, 256, 0)
            == hipSuccess && nb > 0) {
        int grid = nb * 256;                 // 256 CUs
        if (grid > NG) grid = NG;
        void* args[] = {
            (void*)&feat, (void*)&dw_w, (void*)&dw_b, (void*)&pw_w, (void*)&pw_b,
            (void*)&k_w, (void*)&v_w, (void*)&out_w, (void*)&out_b,
            (void*)&dwout, (void*)&VP8, (void*)&out
        };
        if (hipLaunchCooperativeKernel((void*)fused_all, dim3(grid), dim3(256),
                                       args, 0, stream) == hipSuccess)
            done = true;
    }

    if (!done) {   // proven three-kernel fallback (R16)
        hipLaunchKernelGGL(dwconv8h, dim3(3456), dim3(256), 0, stream,
                           feat, dw_w, dw_b, dwout);
        hipLaunchKernelGGL(pwk, dim3(NPOS / 128), dim3(256), 0, stream,
                           dwout, pw_w, pw_b, k_w, v_w, out_w, VP8);
        hipLaunchKernelGGL(attn_vp, dim3(NG), dim3(256), 0, stream,
                           VP8, out_b, out);
    }
}

// Round 21
// 67.162 us; speedup vs baseline: 3.8777x; 3.8777x over previous
//
#include <hip/hip_runtime.h>
#include <hip/hip_fp16.h>
#include <stdint.h>

#define DIN 96
#define DP 48
#define NPOS (48*48*48)   // 110592
#define NG 1728           // 12^3
#define WIN3 343
#define NCH 64
#define NC2 32

// ---------------------------------------------------------------------------
// Kernel A: depthwise 3x3x3 stride-2 pad-1 conv + bias -> dwout[c][pos] fp16
// BRANCHLESS: boundary rows use clamped (always-valid) addresses and a
// per-row weight mask, so all 45 row-loads are unconditionally issuable and
// the scheduler can pipeline them. 2(d)x1(h)x4(w) outputs/thread,
// 3456 blocks, XCD-chunked swizzle.
// ---------------------------------------------------------------------------
__global__ __launch_bounds__(256) void dwconv8h(
    const float* __restrict__ feat,   // [64][96][96][96]
    const float* __restrict__ dw_w,   // [64][27]
    const float* __restrict__ dw_b,   // [64]
    __half* __restrict__ dwout)       // [64][NPOS] fp16
{
    const int bid  = blockIdx.x;
    const int orig = (bid & 7) * 432 + (bid >> 3);    // XCD-chunked swizzle
    const int c    = orig / 54;
    const int bx   = orig % 54;

    const int idx = bx * 256 + threadIdx.x;           // 0..13823
    const int t   = idx % 12;                         // w-quad (ow = 4t..4t+3)
    const int oh  = (idx / 12) % 48;
    const int odp = idx / (12 * 48);                  // d-pair (od = 2odp,2odp+1)

    const float* fc = feat + (size_t)c * (DIN * DIN * DIN);
    const float* wc = dw_w + c * 27;
    float w[27];
    #pragma unroll
    for (int i = 0; i < 27; ++i) w[i] = wc[i];        // wave-uniform -> SGPRs

    float acc[2][4];
    #pragma unroll
    for (int i = 0; i < 2; ++i)
        #pragma unroll
        for (int j = 0; j < 4; ++j) acc[i][j] = 0.0f;

    #pragma unroll
    for (int dd = 0; dd < 5; ++dd) {
        const int id   = 4 * odp - 1 + dd;            // input plane (-1..95)
        const int idc  = (id < 0) ? 0 : id;           // clamped (valid) plane
        const float dm = (id < 0) ? 0.0f : 1.0f;
        #pragma unroll
        for (int kh = 0; kh < 3; ++kh) {
            const int ih    = 2 * oh - 1 + kh;        // input row (-1..95)
            const int ihc   = (ih < 0) ? 0 : ih;
            const float msk = (ih < 0) ? 0.0f : dm;

            const float* row = fc + ((size_t)idc * DIN + ihc) * DIN + 8 * t;
            const float4 a4 = *(const float4*)(row);
            const float4 b4 = *(const float4*)(row + 4);
            const float  s  = (t > 0) ? row[-1] : 0.0f;   // w = 8t-1 (pad 0)

            #pragma unroll
            for (int half = 0; half < 2; ++half) {
                if ((half == 0 && dd <= 2) || (half == 1 && dd >= 2)) {  // compile-time
                    const int kd = dd - 2 * half;
                    const float w0 = w[(kd * 3 + kh) * 3 + 0] * msk;
                    const float w1 = w[(kd * 3 + kh) * 3 + 1] * msk;
                    const float w2 = w[(kd * 3 + kh) * 3 + 2] * msk;
                    acc[half][0] = fmaf(s,    w0, fmaf(a4.x, w1, fmaf(a4.y, w2, acc[half][0])));
                    acc[half][1] = fmaf(a4.y, w0, fmaf(a4.z, w1, fmaf(a4.w, w2, acc[half][1])));
                    acc[half][2] = fmaf(a4.w, w0, fmaf(b4.x, w1, fmaf(b4.y, w2, acc[half][2])));
                    acc[half][3] = fmaf(b4.y, w0, fmaf(b4.z, w1, fmaf(b4.w, w2, acc[half][3])));
                }
            }
        }
    }

    const float b = dw_b[c];
    const size_t base = (size_t)c * NPOS + (((size_t)(2 * odp) * DP + oh) * DP) + 4 * t;
    {
        float2 pk;
        ((__half2*)&pk)[0] = __floats2half2_rn(acc[0][0] + b, acc[0][1] + b);
        ((__half2*)&pk)[1] = __floats2half2_rn(acc[0][2] + b, acc[0][3] + b);
        *(float2*)(dwout + base) = pk;
    }
    {
        float2 pk;
        ((__half2*)&pk)[0] = __floats2half2_rn(acc[1][0] + b, acc[1][1] + b);
        ((__half2*)&pk)[1] = __floats2half2_rn(acc[1][2] + b, acc[1][3] + b);
        *(float2*)(dwout + base + DP * DP) = pk;
    }
}

// ---------------------------------------------------------------------------
// Kernel B (fused pw1+kvp8, fp16 input): pointwise(64->32)+ReLU then
// prefolded K/V-projection -> VP8[NPOS][8].  (~7.7us — near floor)
// ---------------------------------------------------------------------------
__global__ __launch_bounds__(256) void pwk(
    const __half* __restrict__ dwout, // [64][NPOS] fp16
    const float* __restrict__ pw_w,   // [32][64]
    const float* __restrict__ pw_b,   // [32]
    const float* __restrict__ k_w,    // [64][32]
    const float* __restrict__ v_w,    // [64][32]
    const float* __restrict__ out_w,  // [3][64]
    float* __restrict__ VP8)          // [NPOS][8]
{
    __shared__ float swT[NCH * NC2];  // swT[c*32+o] = pw_w[o*64+c]
    __shared__ float sb[NC2];
    __shared__ float WC[8][NC2];
    __shared__ float f2s[128][33];
    const int tid = threadIdx.x;

    for (int i = tid; i < NCH * NC2; i += 256) {
        const int o = i & 31, c = i >> 5;
        swT[i] = pw_w[o * NCH + c];
    }
    if (tid < NC2) sb[tid] = pw_b[tid];
    if (tid < 64) {                   // K rows, prescaled
        const int h = tid >> 5, o = tid & 31;
        WC[h][o] = k_w[(h * 32) * NC2 + o] * 0.17677669529663687f;
    } else {                          // W2 rows, r=0..5
        const int r = (tid - 64) >> 5, k = (tid - 64) & 31;
        const int h = r / 3, oo = r % 3;
        float a = 0.f;
        #pragma unroll
        for (int c = 0; c < NC2; ++c)
            a = fmaf(out_w[oo * NCH + h * 32 + c], v_w[(h * 32 + c) * NC2 + k], a);
        WC[2 + r][k] = a;
    }
    __syncthreads();

    const int oq = tid & 7;           // out-ch group: 4*oq .. 4*oq+3
    const int p4 = tid >> 3;          // local position quad 0..31
    const size_t pos0 = (size_t)blockIdx.x * 128;

    float acc[4][4];                  // [ch][pos]
    #pragma unroll
    for (int i = 0; i < 4; ++i) {
        const float b = sb[oq * 4 + i];
        #pragma unroll
        for (int j = 0; j < 4; ++j) acc[i][j] = b;
    }

    const __half* xp = dwout + pos0 + 4 * (size_t)p4;
    #pragma unroll 4
    for (int c = 0; c < NCH; ++c) {
        const float2 raw = *(const float2*)(xp + (size_t)c * NPOS);
        const float2 x01 = __half22float2(((const __half2*)&raw)[0]);
        const float2 x23 = __half22float2(((const __half2*)&raw)[1]);
        const float4 w4 = *(const float4*)(swT + c * NC2 + oq * 4);
        const float xs[4] = {x01.x, x01.y, x23.x, x23.y};
        const float ws[4] = {w4.x, w4.y, w4.z, w4.w};
        #pragma unroll
        for (int i = 0; i < 4; ++i)
            #pragma unroll
            for (int j = 0; j < 4; ++j)
                acc[i][j] = fmaf(ws[i], xs[j], acc[i][j]);
    }

    #pragma unroll
    for (int j = 0; j < 4; ++j) {
        const int pl = p4 * 4 + j;
        #pragma unroll
        for (int i = 0; i < 4; ++i)
            f2s[pl][oq * 4 + i] = fmaxf(acc[i][j], 0.f);
    }
    __syncthreads();

    const int q  = tid & 1;           // output group q*4..q*4+3
    const int pl = tid >> 1;          // local position 0..127
    float a8[4] = {0.f, 0.f, 0.f, 0.f};
    #pragma unroll 8
    for (int o = 0; o < NC2; ++o) {
        const float x = f2s[pl][o];
        #pragma unroll
        for (int r = 0; r < 4; ++r)
            a8[r] = fmaf(WC[q * 4 + r][o], x, a8[r]);
    }
    *(float4*)(VP8 + (pos0 + pl) * 8 + q * 4) = make_float4(a8[0], a8[1], a8[2], a8[3]);
}

// ---------------------------------------------------------------------------
// Kernel C: windowed attention from VP8 (~5.5us — near floor).
// ---------------------------------------------------------------------------
__global__ __launch_bounds__(256) void attn_vp(
    const float* __restrict__ VP8,    // [NPOS][8]
    const float* __restrict__ out_b,  // [3]
    float* __restrict__ out)          // [3][NG]
{
    const int lo_t[12] = {0,1,5,9,14,18,22,26,31,35,39,44};
    const int hi_t[12] = {4,8,12,16,21,25,29,33,38,42,46,48};

    const int g    = blockIdx.x;
    const int tid  = threadIdx.x;
    const int lane = tid & 63;
    const int wv   = tid >> 6;

    const int gz = g % 12, gy = (g / 12) % 12, gx = g / 144;
    const int lox = lo_t[gx], hix = hi_t[gx];
    const int loy = lo_t[gy], hiy = hi_t[gy];
    const int loz = lo_t[gz], hiz = hi_t[gz];

    const float NEG_INF = -__builtin_inff();

    float4 lo0, hi0, lo1, hi1;
    {
        const int s = tid;
        const int kd = s / 49, kh = (s / 7) % 7, kw = s % 7;
        const int ix = lox + kd, iy = loy + kh, iz = loz + kw;
        if (ix < hix && iy < hiy && iz < hiz) {
            const int fv = (ix * DP + iy) * DP + iz;
            const float4* p = (const float4*)(VP8 + (size_t)fv * 8);
            lo0 = p[0]; hi0 = p[1];
        } else {
            lo0 = make_float4(NEG_INF, NEG_INF, 0.f, 0.f);
            hi0 = make_float4(0.f, 0.f, 0.f, 0.f);
        }
    }
    {
        const int s = tid + 256;
        lo1 = make_float4(NEG_INF, NEG_INF, 0.f, 0.f);
        hi1 = make_float4(0.f, 0.f, 0.f, 0.f);
        if (s < WIN3) {
            const int kd = s / 49, kh = (s / 7) % 7, kw = s % 7;
            const int ix = lox + kd, iy = loy + kh, iz = loz + kw;
            if (ix < hix && iy < hiy && iz < hiz) {
                const int fv = (ix * DP + iy) * DP + iz;
                const float4* p = (const float4*)(VP8 + (size_t)fv * 8);
                lo1 = p[0]; hi1 = p[1];
            }
        }
    }

    __shared__ float sred[4][8];

    float m0 = fmaxf(lo0.x, lo1.x);
    float m1 = fmaxf(lo0.y, lo1.y);
    #pragma unroll
    for (int off = 32; off; off >>= 1) {
        m0 = fmaxf(m0, __shfl_xor(m0, off));
        m1 = fmaxf(m1, __shfl_xor(m1, off));
    }
    if (lane == 0) { sred[wv][0] = m0; sred[wv][1] = m1; }
    __syncthreads();
    const float g0 = fmaxf(fmaxf(sred[0][0], sred[1][0]), fmaxf(sred[2][0], sred[3][0]));
    const float g1 = fmaxf(fmaxf(sred[0][1], sred[1][1]), fmaxf(sred[2][1], sred[3][1]));
    __syncthreads();

    const float e00 = expf(lo0.x - g0), e01 = expf(lo0.y - g1);
    const float e10 = expf(lo1.x - g0), e11 = expf(lo1.y - g1);

    float acc[8];
    acc[0] = e00 + e10;
    acc[1] = e01 + e11;
    acc[2] = e00 * lo0.z + e10 * lo1.z;
    acc[3] = e00 * lo0.w + e10 * lo1.w;
    acc[4] = e00 * hi0.x + e10 * hi1.x;
    acc[5] = e01 * hi0.y + e11 * hi1.y;
    acc[6] = e01 * hi0.z + e11 * hi1.z;
    acc[7] = e01 * hi0.w + e11 * hi1.w;

    #pragma unroll
    for (int j = 0; j < 8; ++j) {
        #pragma unroll
        for (int off = 32; off; off >>= 1) acc[j] += __shfl_xor(acc[j], off);
    }
    if (lane == 0) {
        #pragma unroll
        for (int j = 0; j < 8; ++j) sred[wv][j] = acc[j];
    }
    __syncthreads();

    if (tid < 3) {
        const float s0 = sred[0][0] + sred[1][0] + sred[2][0] + sred[3][0];
        const float s1 = sred[0][1] + sred[1][1] + sred[2][1] + sred[3][1];
        const float a0 = sred[0][2 + tid] + sred[1][2 + tid] + sred[2][2 + tid] + sred[3][2 + tid];
        const float a1 = sred[0][5 + tid] + sred[1][5 + tid] + sred[2][5 + tid] + sred[3][5 + tid];
        out[tid * NG + g] = out_b[tid] + a0 / s0 + a1 / s1;
    }
}

// ---------------------------------------------------------------------------
extern "C" void kernel_launch(void* const* d_in, const int* in_sizes, int n_in,
                              void* d_out, int out_size, void* d_ws, size_t ws_size,
                              hipStream_t stream) {
    const float* feat  = (const float*)d_in[0];
    const float* dw_w  = (const float*)d_in[1];
    const float* dw_b  = (const float*)d_in[2];
    const float* pw_w  = (const float*)d_in[3];
    const float* pw_b  = (const float*)d_in[4];
    const float* k_w   = (const float*)d_in[5];
    const float* v_w   = (const float*)d_in[6];
    const float* out_w = (const float*)d_in[7];
    const float* out_b = (const float*)d_in[8];
    float* out = (float*)d_out;

    __half* dwout = (__half*)d_ws;                              // [64][NPOS] 14 MB
    float*  VP8   = (float*)(dwout + (size_t)NCH * NPOS);       // [NPOS][8] 3.5 MB

    hipLaunchKernelGGL(dwconv8h, dim3(3456), dim3(256), 0, stream,
                       feat, dw_w, dw_b, dwout);
    hipLaunchKernelGGL(pwk, dim3(NPOS / 128), dim3(256), 0, stream,   // 864 blocks
                       dwout, pw_w, pw_b, k_w, v_w, out_w, VP8);
    hipLaunchKernelGGL(attn_vp, dim3(NG), dim3(256), 0, stream,
                       VP8, out_b, out);
}

// Round 22
// 67.160 us; speedup vs baseline: 3.8778x; 1.0000x over previous
//
#include <hip/hip_runtime.h>
#include <hip/hip_fp16.h>
#include <stdint.h>

#define DIN 96
#define DP 48
#define NPOS (48*48*48)   // 110592
#define NG 1728           // 12^3
#define WIN3 343
#define NCH 64
#define NC2 32

// ---------------------------------------------------------------------------
// Kernel A: depthwise 3x3x3 s2 p1 conv + bias -> dwout[c][pos] fp16
// BRANCHLESS + FULL PREFETCH: all 15 rows (45 loads) issued into registers
// before any FMA -> max memory-level parallelism. Boundary rows use clamped
// addresses + zero weight mask. 2(d)x1(h)x4(w)/thread, 3456 blocks, XCD swz.
// ---------------------------------------------------------------------------
__global__ __launch_bounds__(256) void dwconv8h(
    const float* __restrict__ feat,   // [64][96][96][96]
    const float* __restrict__ dw_w,   // [64][27]
    const float* __restrict__ dw_b,   // [64]
    __half* __restrict__ dwout)       // [64][NPOS] fp16
{
    const int bid  = blockIdx.x;
    const int orig = (bid & 7) * 432 + (bid >> 3);    // XCD-chunked swizzle
    const int c    = orig / 54;
    const int bx   = orig % 54;

    const int idx = bx * 256 + threadIdx.x;           // 0..13823
    const int t   = idx % 12;                         // w-quad (ow = 4t..4t+3)
    const int oh  = (idx / 12) % 48;
    const int odp = idx / (12 * 48);                  // d-pair (od = 2odp,2odp+1)

    const float* fc = feat + (size_t)c * (DIN * DIN * DIN);
    const float* wc = dw_w + c * 27;
    float w[27];
    #pragma unroll
    for (int i = 0; i < 27; ++i) w[i] = wc[i];        // wave-uniform -> SGPRs

    // ---- issue ALL 45 row-loads before any FMA ----
    float4 A[15], B[15];
    float  S[15];
    float  M[15];
    #pragma unroll
    for (int dd = 0; dd < 5; ++dd) {
        const int id   = 4 * odp - 1 + dd;            // -1..95
        const int idc  = (id < 0) ? 0 : id;
        const float dm = (id < 0) ? 0.0f : 1.0f;
        #pragma unroll
        for (int kh = 0; kh < 3; ++kh) {
            const int r    = dd * 3 + kh;
            const int ih   = 2 * oh - 1 + kh;         // -1..95
            const int ihc  = (ih < 0) ? 0 : ih;
            M[r] = (ih < 0) ? 0.0f : dm;
            const float* row = fc + ((size_t)idc * DIN + ihc) * DIN + 8 * t;
            A[r] = *(const float4*)(row);
            B[r] = *(const float4*)(row + 4);
            S[r] = (t > 0) ? row[-1] : 0.0f;
        }
    }

    // ---- all FMAs ----
    float acc[2][4];
    #pragma unroll
    for (int i = 0; i < 2; ++i)
        #pragma unroll
        for (int j = 0; j < 4; ++j) acc[i][j] = 0.0f;

    #pragma unroll
    for (int dd = 0; dd < 5; ++dd) {
        #pragma unroll
        for (int kh = 0; kh < 3; ++kh) {
            const int r = dd * 3 + kh;
            const float4 a4 = A[r];
            const float4 b4 = B[r];
            const float  s  = S[r];
            const float  m  = M[r];
            #pragma unroll
            for (int half = 0; half < 2; ++half) {
                if ((half == 0 && dd <= 2) || (half == 1 && dd >= 2)) {  // compile-time
                    const int kd = dd - 2 * half;
                    const float w0 = w[(kd * 3 + kh) * 3 + 0] * m;
                    const float w1 = w[(kd * 3 + kh) * 3 + 1] * m;
                    const float w2 = w[(kd * 3 + kh) * 3 + 2] * m;
                    acc[half][0] = fmaf(s,    w0, fmaf(a4.x, w1, fmaf(a4.y, w2, acc[half][0])));
                    acc[half][1] = fmaf(a4.y, w0, fmaf(a4.z, w1, fmaf(a4.w, w2, acc[half][1])));
                    acc[half][2] = fmaf(a4.w, w0, fmaf(b4.x, w1, fmaf(b4.y, w2, acc[half][2])));
                    acc[half][3] = fmaf(b4.y, w0, fmaf(b4.z, w1, fmaf(b4.w, w2, acc[half][3])));
                }
            }
        }
    }

    const float b = dw_b[c];
    const size_t base = (size_t)c * NPOS + (((size_t)(2 * odp) * DP + oh) * DP) + 4 * t;
    {
        float2 pk;
        ((__half2*)&pk)[0] = __floats2half2_rn(acc[0][0] + b, acc[0][1] + b);
        ((__half2*)&pk)[1] = __floats2half2_rn(acc[0][2] + b, acc[0][3] + b);
        *(float2*)(dwout + base) = pk;
    }
    {
        float2 pk;
        ((__half2*)&pk)[0] = __floats2half2_rn(acc[1][0] + b, acc[1][1] + b);
        ((__half2*)&pk)[1] = __floats2half2_rn(acc[1][2] + b, acc[1][3] + b);
        *(float2*)(dwout + base + DP * DP) = pk;
    }
}

// ---------------------------------------------------------------------------
// Kernel B (fused pw1+kvp8, fp16 input): pointwise(64->32)+ReLU then
// prefolded K/V-projection -> VP8[NPOS][8].  (~7.7us — near floor)
// ---------------------------------------------------------------------------
__global__ __launch_bounds__(256) void pwk(
    const __half* __restrict__ dwout, // [64][NPOS] fp16
    const float* __restrict__ pw_w,   // [32][64]
    const float* __restrict__ pw_b,   // [32]
    const float* __restrict__ k_w,    // [64][32]
    const float* __restrict__ v_w,    // [64][32]
    const float* __restrict__ out_w,  // [3][64]
    float* __restrict__ VP8)          // [NPOS][8]
{
    __shared__ float swT[NCH * NC2];  // swT[c*32+o] = pw_w[o*64+c]
    __shared__ float sb[NC2];
    __shared__ float WC[8][NC2];
    __shared__ float f2s[128][33];
    const int tid = threadIdx.x;

    for (int i = tid; i < NCH * NC2; i += 256) {
        const int o = i & 31, c = i >> 5;
        swT[i] = pw_w[o * NCH + c];
    }
    if (tid < NC2) sb[tid] = pw_b[tid];
    if (tid < 64) {                   // K rows, prescaled
        const int h = tid >> 5, o = tid & 31;
        WC[h][o] = k_w[(h * 32) * NC2 + o] * 0.17677669529663687f;
    } else {                          // W2 rows, r=0..5
        const int r = (tid - 64) >> 5, k = (tid - 64) & 31;
        const int h = r / 3, oo = r % 3;
        float a = 0.f;
        #pragma unroll
        for (int c = 0; c < NC2; ++c)
            a = fmaf(out_w[oo * NCH + h * 32 + c], v_w[(h * 32 + c) * NC2 + k], a);
        WC[2 + r][k] = a;
    }
    __syncthreads();

    const int oq = tid & 7;           // out-ch group: 4*oq .. 4*oq+3
    const int p4 = tid >> 3;          // local position quad 0..31
    const size_t pos0 = (size_t)blockIdx.x * 128;

    float acc[4][4];                  // [ch][pos]
    #pragma unroll
    for (int i = 0; i < 4; ++i) {
        const float b = sb[oq * 4 + i];
        #pragma unroll
        for (int j = 0; j < 4; ++j) acc[i][j] = b;
    }

    const __half* xp = dwout + pos0 + 4 * (size_t)p4;
    #pragma unroll 4
    for (int c = 0; c < NCH; ++c) {
        const float2 raw = *(const float2*)(xp + (size_t)c * NPOS);
        const float2 x01 = __half22float2(((const __half2*)&raw)[0]);
        const float2 x23 = __half22float2(((const __half2*)&raw)[1]);
        const float4 w4 = *(const float4*)(swT + c * NC2 + oq * 4);
        const float xs[4] = {x01.x, x01.y, x23.x, x23.y};
        const float ws[4] = {w4.x, w4.y, w4.z, w4.w};
        #pragma unroll
        for (int i = 0; i < 4; ++i)
            #pragma unroll
            for (int j = 0; j < 4; ++j)
                acc[i][j] = fmaf(ws[i], xs[j], acc[i][j]);
    }

    #pragma unroll
    for (int j = 0; j < 4; ++j) {
        const int pl = p4 * 4 + j;
        #pragma unroll
        for (int i = 0; i < 4; ++i)
            f2s[pl][oq * 4 + i] = fmaxf(acc[i][j], 0.f);
    }
    __syncthreads();

    const int q  = tid & 1;           // output group q*4..q*4+3
    const int pl = tid >> 1;          // local position 0..127
    float a8[4] = {0.f, 0.f, 0.f, 0.f};
    #pragma unroll 8
    for (int o = 0; o < NC2; ++o) {
        const float x = f2s[pl][o];
        #pragma unroll
        for (int r = 0; r < 4; ++r)
            a8[r] = fmaf(WC[q * 4 + r][o], x, a8[r]);
    }
    *(float4*)(VP8 + (pos0 + pl) * 8 + q * 4) = make_float4(a8[0], a8[1], a8[2], a8[3]);
}

// ---------------------------------------------------------------------------
// Kernel C: windowed attention from VP8 (~5.5us — near floor).
// ---------------------------------------------------------------------------
__global__ __launch_bounds__(256) void attn_vp(
    const float* __restrict__ VP8,    // [NPOS][8]
    const float* __restrict__ out_b,  // [3]
    float* __restrict__ out)          // [3][NG]
{
    const int lo_t[12] = {0,1,5,9,14,18,22,26,31,35,39,44};
    const int hi_t[12] = {4,8,12,16,21,25,29,33,38,42,46,48};

    const int g    = blockIdx.x;
    const int tid  = threadIdx.x;
    const int lane = tid & 63;
    const int wv   = tid >> 6;

    const int gz = g % 12, gy = (g / 12) % 12, gx = g / 144;
    const int lox = lo_t[gx], hix = hi_t[gx];
    const int loy = lo_t[gy], hiy = hi_t[gy];
    const int loz = lo_t[gz], hiz = hi_t[gz];

    const float NEG_INF = -__builtin_inff();

    float4 lo0, hi0, lo1, hi1;
    {
        const int s = tid;
        const int kd = s / 49, kh = (s / 7) % 7, kw = s % 7;
        const int ix = lox + kd, iy = loy + kh, iz = loz + kw;
        if (ix < hix && iy < hiy && iz < hiz) {
            const int fv = (ix * DP + iy) * DP + iz;
            const float4* p = (const float4*)(VP8 + (size_t)fv * 8);
            lo0 = p[0]; hi0 = p[1];
        } else {
            lo0 = make_float4(NEG_INF, NEG_INF, 0.f, 0.f);
            hi0 = make_float4(0.f, 0.f, 0.f, 0.f);
        }
    }
    {
        const int s = tid + 256;
        lo1 = make_float4(NEG_INF, NEG_INF, 0.f, 0.f);
        hi1 = make_float4(0.f, 0.f, 0.f, 0.f);
        if (s < WIN3) {
            const int kd = s / 49, kh = (s / 7) % 7, kw = s % 7;
            const int ix = lox + kd, iy = loy + kh, iz = loz + kw;
            if (ix < hix && iy < hiy && iz < hiz) {
                const int fv = (ix * DP + iy) * DP + iz;
                const float4* p = (const float4*)(VP8 + (size_t)fv * 8);
                lo1 = p[0]; hi1 = p[1];
            }
        }
    }

    __shared__ float sred[4][8];

    float m0 = fmaxf(lo0.x, lo1.x);
    float m1 = fmaxf(lo0.y, lo1.y);
    #pragma unroll
    for (int off = 32; off; off >>= 1) {
        m0 = fmaxf(m0, __shfl_xor(m0, off));
        m1 = fmaxf(m1, __shfl_xor(m1, off));
    }
    if (lane == 0) { sred[wv][0] = m0; sred[wv][1] = m1; }
    __syncthreads();
    const float g0 = fmaxf(fmaxf(sred[0][0], sred[1][0]), fmaxf(sred[2][0], sred[3][0]));
    const float g1 = fmaxf(fmaxf(sred[0][1], sred[1][1]), fmaxf(sred[2][1], sred[3][1]));
    __syncthreads();

    const float e00 = expf(lo0.x - g0), e01 = expf(lo0.y - g1);
    const float e10 = expf(lo1.x - g0), e11 = expf(lo1.y - g1);

    float acc[8];
    acc[0] = e00 + e10;
    acc[1] = e01 + e11;
    acc[2] = e00 * lo0.z + e10 * lo1.z;
    acc[3] = e00 * lo0.w + e10 * lo1.w;
    acc[4] = e00 * hi0.x + e10 * hi1.x;
    acc[5] = e01 * hi0.y + e11 * hi1.y;
    acc[6] = e01 * hi0.z + e11 * hi1.z;
    acc[7] = e01 * hi0.w + e11 * hi1.w;

    #pragma unroll
    for (int j = 0; j < 8; ++j) {
        #pragma unroll
        for (int off = 32; off; off >>= 1) acc[j] += __shfl_xor(acc[j], off);
    }
    if (lane == 0) {
        #pragma unroll
        for (int j = 0; j < 8; ++j) sred[wv][j] = acc[j];
    }
    __syncthreads();

    if (tid < 3) {
        const float s0 = sred[0][0] + sred[1][0] + sred[2][0] + sred[3][0];
        const float s1 = sred[0][1] + sred[1][1] + sred[2][1] + sred[3][1];
        const float a0 = sred[0][2 + tid] + sred[1][2 + tid] + sred[2][2 + tid] + sred[3][2 + tid];
        const float a1 = sred[0][5 + tid] + sred[1][5 + tid] + sred[2][5 + tid] + sred[3][5 + tid];
        out[tid * NG + g] = out_b[tid] + a0 / s0 + a1 / s1;
    }
}

// ---------------------------------------------------------------------------
extern "C" void kernel_launch(void* const* d_in, const int* in_sizes, int n_in,
                              void* d_out, int out_size, void* d_ws, size_t ws_size,
                              hipStream_t stream) {
    const float* feat  = (const float*)d_in[0];
    const float* dw_w  = (const float*)d_in[1];
    const float* dw_b  = (const float*)d_in[2];
    const float* pw_w  = (const float*)d_in[3];
    const float* pw_b  = (const float*)d_in[4];
    const float* k_w   = (const float*)d_in[5];
    const float* v_w   = (const float*)d_in[6];
    const float* out_w = (const float*)d_in[7];
    const float* out_b = (const float*)d_in[8];
    float* out = (float*)d_out;

    __half* dwout = (__half*)d_ws;                              // [64][NPOS] 14 MB
    float*  VP8   = (float*)(dwout + (size_t)NCH * NPOS);       // [NPOS][8] 3.5 MB

    hipLaunchKernelGGL(dwconv8h, dim3(3456), dim3(256), 0, stream,
                       feat, dw_w, dw_b, dwout);
    hipLaunchKernelGGL(pwk, dim3(NPOS / 128), dim3(256), 0, stream,   // 864 blocks
                       dwout, pw_w, pw_b, k_w, v_w, out_w, VP8);
    hipLaunchKernelGGL(attn_vp, dim3(NG), dim3(256), 0, stream,
                       VP8, out_b, out);
}